// Round 3
// baseline (7482.352 us; speedup 1.0000x reference)
//
#include <hip/hip_runtime.h>

#define E_ 256
#define H_ 512
#define V_ 32000
#define T_ 32
#define LGRID 250   // blocks that own a 128-col vocab chunk
#define VC_ 128
#define NBLK 256    // == CU count: every block resident on its own CU

typedef short s16x8 __attribute__((ext_vector_type(8)));
typedef float f32x4 __attribute__((ext_vector_type(4)));
typedef int   i32x4 __attribute__((ext_vector_type(4)));

union US8 { i32x4 i; s16x8 s; };

static __device__ __forceinline__ f32x4 mfma16(s16x8 a, s16x8 b, f32x4 c){
  return __builtin_amdgcn_mfma_f32_16x16x32_bf16(a, b, c, 0, 0, 0);
}

static __device__ __forceinline__ unsigned rne(unsigned u){
  return u + 0x7FFFu + ((u >> 16) & 1u);
}

static __device__ __forceinline__ void split_f(float f, unsigned short &hs, unsigned short &ls){
  unsigned r = rne(__float_as_uint(f));
  hs = (unsigned short)(r >> 16);
  float fh = __uint_as_float(r & 0xFFFF0000u);
  unsigned r2 = rne(__float_as_uint(f - fh));
  ls = (unsigned short)(r2 >> 16);
}

// 8 consecutive f32 -> bf16 hi (RNE) + bf16 of residual
static __device__ __forceinline__ void split8(f32x4 a0, f32x4 a1, s16x8 &hi, s16x8 &lo){
  float f[8]; unsigned r[8];
  #pragma unroll
  for (int j=0;j<4;j++){ f[j] = a0[j]; f[4+j] = a1[j]; }
  #pragma unroll
  for (int j=0;j<8;j++) r[j] = rne(__float_as_uint(f[j]));
  US8 Hh, Ll;
  #pragma unroll
  for (int p=0;p<4;p++) Hh.i[p] = (int)__builtin_amdgcn_perm(r[2*p+1], r[2*p], 0x07060302u);
  unsigned d[8];
  #pragma unroll
  for (int j=0;j<8;j++) d[j] = rne(__float_as_uint(f[j] - __uint_as_float(r[j] & 0xFFFF0000u)));
  #pragma unroll
  for (int p=0;p<4;p++) Ll.i[p] = (int)__builtin_amdgcn_perm(d[2*p+1], d[2*p], 0x07060302u);
  hi = Hh.s; lo = Ll.s;
}

// ---------------------------------------------------------------------------
// Fence-hardened monotonic grid barrier (single counter, never reset).
// Works under a PLAIN launch because grid == 256 blocks on 256 CUs with
// <160KB LDS each: all blocks are co-resident from dispatch (persistent-
// kernel contract). Release: syncthreads -> threadfence by EVERY wave ->
// syncthreads -> leader SEQ_CST/SYSTEM arrival add. Acquire: leader spin
// (SEQ_CST/SYSTEM) -> syncthreads -> threadfence before post-barrier loads.
// ---------------------------------------------------------------------------
static __device__ __forceinline__ void gridbar(int* bar, int use){
  __syncthreads();
  __threadfence();
  __syncthreads();
  if (threadIdx.x == 0){
    __hip_atomic_fetch_add(bar, 1, __ATOMIC_SEQ_CST, __HIP_MEMORY_SCOPE_SYSTEM);
    while (__hip_atomic_load(bar, __ATOMIC_SEQ_CST, __HIP_MEMORY_SCOPE_SYSTEM) < (use+1)*NBLK)
      __builtin_amdgcn_s_sleep(8);
  }
  __syncthreads();
  __threadfence();
}

// ---------------------------------------------------------------------------
// Persistent kernel: init + 32 x {gates | logits | final} + tail.
// xh layout per batch (stride 1280 shorts): [0,256)=x, [256,768)=h buf0,
// [768,1280)=h buf1 (double-buffered h removes the gates read/write race).
// slab (exps of step s) survives in LDS across the barrier and is written
// to out row s-2, normalized, during phase G of step s+1 (overlapped with
// gates; eliminates the raw-write + re-read + rescale triple pass).
// ---------------------------------------------------------------------------
__global__ __launch_bounds__(256) void mega_kernel(
    const float* __restrict__ feat, const float* __restrict__ emb,
    const float* __restrict__ Wih, const float* __restrict__ Whh,
    const float* __restrict__ bih, const float* __restrict__ bhh,
    const float* __restrict__ Wfc, const float* __restrict__ bfc,
    float* __restrict__ out,
    unsigned short* __restrict__ xh_hi, unsigned short* __restrict__ xh_lo,
    float* __restrict__ psum, float* __restrict__ pmaxv, int* __restrict__ pmaxi,
    float* __restrict__ invs, int* __restrict__ bar)
{
  const int blk = blockIdx.x, t = threadIdx.x;
  const int wv = t >> 6, lq = (t >> 4) & 3, ln = t & 15;
  __shared__ float red[8192];     // MFMA cross-wave reduce (both phases)
  __shared__ float slab[8192];    // [64 b][128 v] exps — persists G<-L
  __shared__ float gbuf[2112];    // gates pointwise staging
  __shared__ float fin[32];       // final-phase scratch

  float creg[2] = {0.f, 0.f};     // LSTM cell state, resident in regs (blk<64)
  int bid = 0;

  // ---- init: x-part = split(features); both h buffers = 0 ----
  if (blk < 64){
    unsigned short hs, lsv; split_f(feat[blk*E_ + t], hs, lsv);
    xh_hi[blk*1280 + t] = hs; xh_lo[blk*1280 + t] = lsv;
  } else if (blk < 128){
    int b = blk - 64;
    unsigned* ph = (unsigned*)(xh_hi + b*1280 + 256);
    unsigned* pl = (unsigned*)(xh_lo + b*1280 + 256);
    ph[t] = 0u; ph[t+256] = 0u; pl[t] = 0u; pl[t+256] = 0u;
  }
  gridbar(bar, bid++);

  #pragma unroll 1
  for (int s = 0; s < T_; ++s){
    // h parity: gates(s) reads rd, writes wr; logits(s) reads wr.
    // s==0 and s==1 both read buf0 (zeros) — matches the reference's
    // discard of the feature-step hidden state, no re-zeroing needed.
    const int wr = (s == 0) ? 1 : (s & 1);
    const int rd = wr ^ 1;

    // ============ phase G: gates (blk<64) + normalized out row s-2 ==========
    if (blk < 64){
      s16x8 Agh[4][6], Agl[4][6];
      #pragma unroll
      for (int m=0;m<4;m++)
        #pragma unroll
        for (int kt=0;kt<6;kt++){
          int br = m*16 + ln;
          int kk = 192*wv + 32*kt + 8*lq;
          int off = (kk < 256) ? kk : (256 + rd*512 + (kk - 256));
          Agh[m][kt] = *(const s16x8*)(xh_hi + br*1280 + off);
          Agl[m][kt] = *(const s16x8*)(xh_lo + br*1280 + off);
        }

      f32x4 acc[2][4];
      #pragma unroll
      for (int g=0;g<2;g++)
        #pragma unroll
        for (int m=0;m<4;m++){ f32x4 z = {0.f,0.f,0.f,0.f}; acc[g][m] = z; }

      #pragma unroll
      for (int g=0;g<2;g++){
        int c = blk*32 + g*16 + ln;
        const float* pih = Wih + (size_t)((c&3)*512 + (c>>2))*256;
        const float* phh = Whh + (size_t)((c&3)*512 + (c>>2))*512;
        #pragma unroll
        for (int kt=0;kt<6;kt++){
          int kg = 192*wv + 32*kt;
          int k  = kg + 8*lq;
          const float* p = (kg < 256) ? (pih + k) : (phh + (k - 256));
          f32x4 a0 = *(const f32x4*)p;
          f32x4 a1 = *(const f32x4*)(p + 4);
          s16x8 Bh, Bl; split8(a0, a1, Bh, Bl);
          #pragma unroll
          for (int m=0;m<4;m++){
            acc[g][m] = mfma16(Agh[m][kt], Bh, acc[g][m]);
            acc[g][m] = mfma16(Agh[m][kt], Bl, acc[g][m]);
            acc[g][m] = mfma16(Agl[m][kt], Bh, acc[g][m]);
          }
        }
      }
      #pragma unroll
      for (int g=0;g<2;g++)
        #pragma unroll
        for (int m=0;m<4;m++){
          int f4 = (((wv*2+g)*4+m)*4+lq)*16 + ln;
          *(f32x4*)(red + f4*4) = acc[g][m];
        }
      __syncthreads();
      #pragma unroll
      for (int g=0;g<2;g++){
        f32x4 v4 = {0.f,0.f,0.f,0.f};
        #pragma unroll
        for (int ww=0;ww<4;ww++){
          int f4 = (((ww*2+g)*4+wv)*4+lq)*16 + ln;
          v4 += *(const f32x4*)(red + f4*4);
        }
        int c = blk*32 + g*16 + ln;
        int row = (c&3)*512 + (c>>2);
        float bias = bih[row] + bhh[row];
        #pragma unroll
        for (int r=0;r<4;r++)
          gbuf[(wv*16 + lq*4 + r)*33 + g*16 + ln] = v4[r] + bias;
      }
      __syncthreads();
      #pragma unroll
      for (int rep=0;rep<2;rep++){
        int p = rep*256 + t;
        int b = p >> 3, ul = p & 7;
        float gi = gbuf[b*33 + ul*4 + 0];
        float gf = gbuf[b*33 + ul*4 + 1];
        float gg = gbuf[b*33 + ul*4 + 2];
        float go = gbuf[b*33 + ul*4 + 3];
        int u = blk*8 + ul;
        float cp = (s <= 1) ? 0.f : creg[rep];   // ref restarts state after feature step
        float si = 1.f/(1.f + __expf(-gi));
        float sf = 1.f/(1.f + __expf(-gf));
        float so = 1.f/(1.f + __expf(-go));
        float cn = sf*cp + si*tanhf(gg);
        creg[rep] = cn;
        float hv = so*tanhf(cn);
        unsigned short hs, lsv; split_f(hv, hs, lsv);
        xh_hi[b*1280 + 256 + wr*512 + u] = hs;
        xh_lo[b*1280 + 256 + wr*512 + u] = lsv;
      }
    }
    // normalized write of row s-2 = slab(s-1) * invs(s-1); overlaps gates
    if (s >= 2 && blk < LGRID){
      #pragma unroll
      for (int i=0;i<8;i++){
        int e = i*256 + t;
        int b = e >> 5;
        int v4 = (e & 31) << 2;
        f32x4 pv = *(const f32x4*)(slab + b*128 + v4);
        pv *= invs[b];
        __builtin_nontemporal_store(pv,
            (f32x4*)(out + ((size_t)b*T_ + (s-2))*V_ + blk*VC_ + v4));
      }
    }
    gridbar(bar, bid++);

    // ===================== phase L: logits + exp + partials ==================
    if (blk < LGRID){
      s16x8 Ah[4][4], Al[4][4];
      #pragma unroll
      for (int m=0;m<4;m++)
        #pragma unroll
        for (int ks=0;ks<4;ks++){
          int br = m*16 + ln;
          int k  = 128*wv + 32*ks + 8*lq;
          int hoff = 256 + wr*512 + k;
          Ah[m][ks] = *(const s16x8*)(xh_hi + br*1280 + hoff);
          Al[m][ks] = *(const s16x8*)(xh_lo + br*1280 + hoff);
        }

      f32x4 rsum = {0.f,0.f,0.f,0.f};
      f32x4 rmax = {-1e30f,-1e30f,-1e30f,-1e30f};
      i32x4 ridx = {0x7fffffff,0x7fffffff,0x7fffffff,0x7fffffff};

      for (int G=0;G<4;G++){
        f32x4 acc[2][4];
        #pragma unroll
        for (int g=0;g<2;g++)
          #pragma unroll
          for (int m=0;m<4;m++){ f32x4 z = {0.f,0.f,0.f,0.f}; acc[g][m] = z; }

        #pragma unroll
        for (int g=0;g<2;g++){
          int vt = G*2 + g;
          const float* wp = Wfc + (size_t)(blk*VC_ + vt*16 + ln)*512 + 128*wv + 8*lq;
          #pragma unroll
          for (int ks=0;ks<4;ks++){
            f32x4 a0 = *(const f32x4*)(wp + 32*ks);
            f32x4 a1 = *(const f32x4*)(wp + 32*ks + 4);
            s16x8 Bh, Bl; split8(a0, a1, Bh, Bl);
            #pragma unroll
            for (int m=0;m<4;m++){
              acc[g][m] = mfma16(Ah[m][ks], Bh, acc[g][m]);
              acc[g][m] = mfma16(Ah[m][ks], Bl, acc[g][m]);
              acc[g][m] = mfma16(Al[m][ks], Bh, acc[g][m]);
            }
          }
        }
        #pragma unroll
        for (int g=0;g<2;g++)
          #pragma unroll
          for (int m=0;m<4;m++){
            int f4 = (((wv*2+g)*4+m)*4+lq)*16 + ln;
            *(f32x4*)(red + f4*4) = acc[g][m];
          }
        __syncthreads();
        #pragma unroll
        for (int g=0;g<2;g++){
          int vt = G*2+g;
          f32x4 v4 = {0.f,0.f,0.f,0.f};
          #pragma unroll
          for (int ww=0;ww<4;ww++){
            int f4 = (((ww*2+g)*4+wv)*4+lq)*16 + ln;
            v4 += *(const f32x4*)(red + f4*4);
          }
          int vg = blk*VC_ + vt*16 + ln;
          float bias = bfc[vg];
          #pragma unroll
          for (int r=0;r<4;r++){
            float pe = __expf(v4[r] + bias);
            slab[(wv*16 + lq*4 + r)*128 + vt*16 + ln] = pe;
            rsum[r] += pe;
            if (pe > rmax[r]){ rmax[r] = pe; ridx[r] = vg; }  // ascending vg keeps first max
          }
        }
        __syncthreads();
      }

      // combine 16 ln-lanes (same batch quad, disjoint vocab cols)
      #pragma unroll
      for (int d2=1; d2<16; d2<<=1){
        #pragma unroll
        for (int r=0;r<4;r++){
          float os = __shfl_xor(rsum[r], d2, 64);
          float ov = __shfl_xor(rmax[r], d2, 64);
          int   oi = __shfl_xor(ridx[r], d2, 64);
          rsum[r] += os;
          if (ov > rmax[r] || (ov == rmax[r] && oi < ridx[r])){ rmax[r]=ov; ridx[r]=oi; }
        }
      }
      if (ln == 0){
        #pragma unroll
        for (int r=0;r<4;r++){
          int b = wv*16 + lq*4 + r;
          psum [b*256 + blk] = rsum[r];
          pmaxv[b*256 + blk] = rmax[r];
          pmaxi[b*256 + blk] = ridx[r];
        }
      }
    }
    gridbar(bar, bid++);

    // ============ phase F: per-batch reduce -> invs, argmax, embed x =========
    if (blk < 64){
      float sv = 0.f, mv = -1e30f; int mi = 0x7fffffff;
      if (t < LGRID){ sv = psum[blk*256+t]; mv = pmaxv[blk*256+t]; mi = pmaxi[blk*256+t]; }
      #pragma unroll
      for (int d2=1; d2<64; d2<<=1){
        float os = __shfl_xor(sv, d2, 64);
        float ov = __shfl_xor(mv, d2, 64);
        int   oi = __shfl_xor(mi, d2, 64);
        sv += os;
        if (ov > mv || (ov == mv && oi < mi)){ mv = ov; mi = oi; }
      }
      if ((t & 63) == 0){ fin[wv] = sv; fin[8+wv] = mv; ((int*)fin)[16+wv] = mi; }
      __syncthreads();
      if (t == 0){
        float S = fin[0]+fin[1]+fin[2]+fin[3];
        float M = -1e30f; int I = 0x7fffffff;
        #pragma unroll
        for (int ww=0;ww<4;ww++){
          float vvv = fin[8+ww]; int ii = ((int*)fin)[16+ww];
          if (vvv > M || (vvv == M && ii < I)){ M = vvv; I = ii; }
        }
        invs[blk] = 1.0f/S;
        ((int*)fin)[20] = I;
      }
      __syncthreads();
      int am = ((int*)fin)[20];
      unsigned short hs, lsv; split_f(emb[(size_t)am*E_ + t], hs, lsv);
      xh_hi[blk*1280 + t] = hs;
      xh_lo[blk*1280 + t] = lsv;
    }
    gridbar(bar, bid++);
  }

  // ---- tail: row 30 = slab(31)*invs(31); row 31 = zeros ----
  if (blk < LGRID){
    #pragma unroll
    for (int i=0;i<8;i++){
      int e = i*256 + t;
      int b = e >> 5;
      int v4 = (e & 31) << 2;
      f32x4 pv = *(const f32x4*)(slab + b*128 + v4);
      pv *= invs[b];
      __builtin_nontemporal_store(pv,
          (f32x4*)(out + ((size_t)b*T_ + 30)*V_ + blk*VC_ + v4));
      f32x4 z = {0.f,0.f,0.f,0.f};
      __builtin_nontemporal_store(z,
          (f32x4*)(out + ((size_t)b*T_ + 31)*V_ + blk*VC_ + v4));
    }
  }
}

extern "C" void kernel_launch(void* const* d_in, const int* in_sizes, int n_in,
                              void* d_out, int out_size, void* d_ws, size_t ws_size,
                              hipStream_t stream){
  const float* feat = (const float*)d_in[0];
  // d_in[1] = captions: unused by the reference computation
  const float* emb  = (const float*)d_in[2];
  const float* Wih  = (const float*)d_in[3];
  const float* Whh  = (const float*)d_in[4];
  const float* bih  = (const float*)d_in[5];
  const float* bhh  = (const float*)d_in[6];
  const float* Wfc  = (const float*)d_in[7];
  const float* bfc  = (const float*)d_in[8];
  float* out = (float*)d_out;

  char* ws = (char*)d_ws;                                   // ~514 KB used
  unsigned short* xh_hi = (unsigned short*)(ws);            // 64x1280 u16
  unsigned short* xh_lo = (unsigned short*)(ws + 163840);   // 64x1280 u16
  float* psum  = (float*)(ws + 327680);                     // [64][256]
  float* pmaxv = (float*)(ws + 393216);                     // [64][256]
  int*   pmaxi = (int*)  (ws + 458752);                     // [64][256]
  float* invs  = (float*)(ws + 524288);                     // [64]
  int*   bar   = (int*)  (ws + 524544);                     // single counter line

  hipMemsetAsync(bar, 0, 128, stream);

  // Plain launch: 256 blocks on 256 CUs, each <160KB LDS -> all co-resident.
  // (hipLaunchCooperativeKernel silently failed to execute in this harness;
  // its error code is unobservable here — R1/R2 absmax equaled max|ref|,
  // i.e. the output buffer was never written.)
  mega_kernel<<<dim3(NBLK), dim3(256), 0, stream>>>(
      feat, emb, Wih, Whh, bih, bhh, Wfc, bfc, out,
      xh_hi, xh_lo, psum, pmaxv, pmaxi, invs, bar);
}

// Round 4
// 4493.353 us; speedup vs baseline: 1.6652x; 1.6652x over previous
//
#include <hip/hip_runtime.h>

#define E_ 256
#define H_ 512
#define V_ 32000
#define T_ 32
#define LGRID 250   // blocks that own a 128-col vocab chunk
#define VC_ 128
#define NBLK 256    // == CU count: every block resident on its own CU

typedef short s16x8 __attribute__((ext_vector_type(8)));
typedef float f32x4 __attribute__((ext_vector_type(4)));
typedef int   i32x4 __attribute__((ext_vector_type(4)));

union US8 { i32x4 i; s16x8 s; };

static __device__ __forceinline__ f32x4 mfma16(s16x8 a, s16x8 b, f32x4 c){
  return __builtin_amdgcn_mfma_f32_16x16x32_bf16(a, b, c, 0, 0, 0);
}

static __device__ __forceinline__ unsigned rne(unsigned u){
  return u + 0x7FFFu + ((u >> 16) & 1u);
}

static __device__ __forceinline__ void split_f(float f, unsigned short &hs, unsigned short &ls){
  unsigned r = rne(__float_as_uint(f));
  hs = (unsigned short)(r >> 16);
  float fh = __uint_as_float(r & 0xFFFF0000u);
  unsigned r2 = rne(__float_as_uint(f - fh));
  ls = (unsigned short)(r2 >> 16);
}

// 8 consecutive f32 -> bf16 hi (RNE) + bf16 of residual
static __device__ __forceinline__ void split8(f32x4 a0, f32x4 a1, s16x8 &hi, s16x8 &lo){
  float f[8]; unsigned r[8];
  #pragma unroll
  for (int j=0;j<4;j++){ f[j] = a0[j]; f[4+j] = a1[j]; }
  #pragma unroll
  for (int j=0;j<8;j++) r[j] = rne(__float_as_uint(f[j]));
  US8 Hh, Ll;
  #pragma unroll
  for (int p=0;p<4;p++) Hh.i[p] = (int)__builtin_amdgcn_perm(r[2*p+1], r[2*p], 0x07060302u);
  unsigned d[8];
  #pragma unroll
  for (int j=0;j<8;j++) d[j] = rne(__float_as_uint(f[j] - __uint_as_float(r[j] & 0xFFFF0000u)));
  #pragma unroll
  for (int p=0;p<4;p++) Ll.i[p] = (int)__builtin_amdgcn_perm(d[2*p+1], d[2*p], 0x07060302u);
  hi = Hh.s; lo = Ll.s;
}

// ---------------------------------------------------------------------------
// Leader-only monotonic grid barrier (single counter, never reset).
// __syncthreads drains each wave's stores to L2 (vmcnt(0) before s_barrier);
// the leader's ACQ_REL/AGENT fetch_add emits the L2 writeback (release) and
// its ACQUIRE/AGENT spin load emits the L2/L1 invalidate (acquire) — cache
// ops are cache-wide and all waves of the block share the CU, so one leader
// covers the block. asm memory clobbers stop compiler-level hoisting.
// This is the cooperative-groups grid.sync() pattern. R3's version had every
// wave doing 2x SYSTEM-scope threadfence: ~75us/barrier -> 7.4ms total.
// ---------------------------------------------------------------------------
static __device__ __forceinline__ void gridbar(int* bar, int tgt){
  __syncthreads();
  asm volatile("" ::: "memory");
  if (threadIdx.x == 0){
    __hip_atomic_fetch_add(bar, 1, __ATOMIC_ACQ_REL, __HIP_MEMORY_SCOPE_AGENT);
    while (__hip_atomic_load(bar, __ATOMIC_ACQUIRE, __HIP_MEMORY_SCOPE_AGENT) < tgt)
      __builtin_amdgcn_s_sleep(2);
  }
  __syncthreads();
  asm volatile("" ::: "memory");
}

// ---------------------------------------------------------------------------
// Persistent kernel, 2 barriers/step:
//   phase A: all blocks reduce partials(s-1) -> invs/am in LDS (redundant,
//            deterministic); blk<64 run gates(s) (x loaded straight from
//            emb[am]/feat, split on the fly; h from xh double-buffer, zeros
//            for s<=1); blk<250 write out row s-2 = slab(s-1)*invs(s-1).
//   phase L: blk<250 logits(s) + exp -> slab (persists in LDS) + partials.
// xh stores h only: per batch stride 1024 shorts = [buf0 512][buf1 512].
// Partials layout [250][64] so the phase-A reduce is wave-coalesced.
// ---------------------------------------------------------------------------
__global__ __launch_bounds__(256) void mega_kernel(
    const float* __restrict__ feat, const float* __restrict__ emb,
    const float* __restrict__ Wih, const float* __restrict__ Whh,
    const float* __restrict__ bih, const float* __restrict__ bhh,
    const float* __restrict__ Wfc, const float* __restrict__ bfc,
    float* __restrict__ out,
    unsigned short* __restrict__ xh_hi, unsigned short* __restrict__ xh_lo,
    float* __restrict__ psum, float* __restrict__ pmaxv, int* __restrict__ pmaxi,
    int* __restrict__ bar)
{
  const int blk = blockIdx.x, t = threadIdx.x;
  const int wv = t >> 6, lq = (t >> 4) & 3, ln = t & 15;
  __shared__ float red[8192];     // MFMA cross-wave reduce + partial staging
  __shared__ float slab[8192];    // [64 b][128 v] exps — persists L -> A
  __shared__ float gbuf[2112];    // gates pointwise staging
  __shared__ float ivs_s[64];     // 1/sum per batch (this step's reduce)
  __shared__ int   am_s[64];      // argmax per batch

  float creg[2] = {0.f, 0.f};     // LSTM cell state in regs (blk<64)
  int cnt = 0;

  #pragma unroll 1
  for (int s = 0; s < T_; ++s){
    const int wr = (s == 0) ? 1 : (s & 1);
    const int rd = wr ^ 1;

    // ================= phase A ==================
    // (A1) redundant per-block reduce of partials(s-1)
    if (s >= 1){
      int b = t & 63, w = t >> 6;
      float sv = 0.f, mv = -1e30f; int mi = 0x7fffffff;
      for (int j = w; j < LGRID; j += 4){
        float s1 = psum [j*64 + b];
        float v1 = pmaxv[j*64 + b];
        int   i1 = pmaxi[j*64 + b];
        sv += s1;
        if (v1 > mv || (v1 == mv && i1 < mi)){ mv = v1; mi = i1; }
      }
      red[w*64 + b] = sv;
      red[256 + w*64 + b] = mv;
      ((int*)red)[512 + w*64 + b] = mi;
      __syncthreads();
      if (t < 64){
        float S = 0.f, M = -1e30f; int I = 0x7fffffff;
        #pragma unroll
        for (int ww=0;ww<4;ww++){
          S += red[ww*64 + t];
          float vv = red[256 + ww*64 + t]; int ii = ((int*)red)[512 + ww*64 + t];
          if (vv > M || (vv == M && ii < I)){ M = vv; I = ii; }
        }
        ivs_s[t] = 1.f/S;
        am_s[t]  = I;
      }
      __syncthreads();
    }

    // (A2) gates on blk<64
    if (blk < 64){
      s16x8 Agh[4][6], Agl[4][6];
      const s16x8 zz = {0,0,0,0,0,0,0,0};
      #pragma unroll
      for (int m=0;m<4;m++)
        #pragma unroll
        for (int kt=0;kt<6;kt++){
          int br = m*16 + ln;
          int kk = 192*wv + 32*kt + 8*lq;
          if (kk < 256){
            const float* p = (s == 0) ? (feat + br*E_ + kk)
                                      : (emb + (size_t)am_s[br]*E_ + kk);
            f32x4 a0 = *(const f32x4*)p;
            f32x4 a1 = *(const f32x4*)(p + 4);
            split8(a0, a1, Agh[m][kt], Agl[m][kt]);
          } else if (s <= 1){
            Agh[m][kt] = zz; Agl[m][kt] = zz;   // h = 0 (ref discards feature-step state)
          } else {
            int off = rd*512 + (kk - 256);
            Agh[m][kt] = *(const s16x8*)(xh_hi + br*1024 + off);
            Agl[m][kt] = *(const s16x8*)(xh_lo + br*1024 + off);
          }
        }

      f32x4 acc[2][4];
      #pragma unroll
      for (int g=0;g<2;g++)
        #pragma unroll
        for (int m=0;m<4;m++){ f32x4 z = {0.f,0.f,0.f,0.f}; acc[g][m] = z; }

      #pragma unroll
      for (int g=0;g<2;g++){
        int c = blk*32 + g*16 + ln;
        const float* pih = Wih + (size_t)((c&3)*512 + (c>>2))*256;
        const float* phh = Whh + (size_t)((c&3)*512 + (c>>2))*512;
        #pragma unroll
        for (int kt=0;kt<6;kt++){
          int kg = 192*wv + 32*kt;
          int k  = kg + 8*lq;
          const float* p = (kg < 256) ? (pih + k) : (phh + (k - 256));
          f32x4 a0 = *(const f32x4*)p;
          f32x4 a1 = *(const f32x4*)(p + 4);
          s16x8 Bh, Bl; split8(a0, a1, Bh, Bl);
          #pragma unroll
          for (int m=0;m<4;m++){
            acc[g][m] = mfma16(Agh[m][kt], Bh, acc[g][m]);
            acc[g][m] = mfma16(Agh[m][kt], Bl, acc[g][m]);
            acc[g][m] = mfma16(Agl[m][kt], Bh, acc[g][m]);
          }
        }
      }
      #pragma unroll
      for (int g=0;g<2;g++)
        #pragma unroll
        for (int m=0;m<4;m++){
          int f4 = (((wv*2+g)*4+m)*4+lq)*16 + ln;
          *(f32x4*)(red + f4*4) = acc[g][m];
        }
      __syncthreads();
      #pragma unroll
      for (int g=0;g<2;g++){
        f32x4 v4 = {0.f,0.f,0.f,0.f};
        #pragma unroll
        for (int ww=0;ww<4;ww++){
          int f4 = (((ww*2+g)*4+wv)*4+lq)*16 + ln;
          v4 += *(const f32x4*)(red + f4*4);
        }
        int c = blk*32 + g*16 + ln;
        int row = (c&3)*512 + (c>>2);
        float bias = bih[row] + bhh[row];
        #pragma unroll
        for (int r=0;r<4;r++)
          gbuf[(wv*16 + lq*4 + r)*33 + g*16 + ln] = v4[r] + bias;
      }
      __syncthreads();
      #pragma unroll
      for (int rep=0;rep<2;rep++){
        int p = rep*256 + t;
        int b = p >> 3, ul = p & 7;
        float gi = gbuf[b*33 + ul*4 + 0];
        float gf = gbuf[b*33 + ul*4 + 1];
        float gg = gbuf[b*33 + ul*4 + 2];
        float go = gbuf[b*33 + ul*4 + 3];
        int u = blk*8 + ul;
        float cp = (s <= 1) ? 0.f : creg[rep];   // ref restarts state after feature step
        float si = 1.f/(1.f + __expf(-gi));
        float sf = 1.f/(1.f + __expf(-gf));
        float so = 1.f/(1.f + __expf(-go));
        float cn = sf*cp + si*tanhf(gg);
        creg[rep] = cn;
        float hv = so*tanhf(cn);
        unsigned short hs, lsv; split_f(hv, hs, lsv);
        xh_hi[b*1024 + wr*512 + u] = hs;
        xh_lo[b*1024 + wr*512 + u] = lsv;
      }
    }

    // (A3) normalized out row s-2 = slab(s-1) * invs(s-1)
    if (s >= 2 && blk < LGRID){
      #pragma unroll
      for (int i=0;i<8;i++){
        int e = i*256 + t;
        int b = e >> 5;
        int v4 = (e & 31) << 2;
        f32x4 pv = *(const f32x4*)(slab + b*128 + v4);
        pv *= ivs_s[b];
        __builtin_nontemporal_store(pv,
            (f32x4*)(out + ((size_t)b*T_ + (s-2))*V_ + blk*VC_ + v4));
      }
    }
    gridbar(bar, ++cnt * NBLK);

    // ================= phase L: logits + exp + partials =================
    if (blk < LGRID){
      s16x8 Ah[4][4], Al[4][4];
      #pragma unroll
      for (int m=0;m<4;m++)
        #pragma unroll
        for (int ks=0;ks<4;ks++){
          int br = m*16 + ln;
          int k  = 128*wv + 32*ks + 8*lq;
          int hoff = wr*512 + k;
          Ah[m][ks] = *(const s16x8*)(xh_hi + br*1024 + hoff);
          Al[m][ks] = *(const s16x8*)(xh_lo + br*1024 + hoff);
        }

      f32x4 rsum = {0.f,0.f,0.f,0.f};
      f32x4 rmax = {-1e30f,-1e30f,-1e30f,-1e30f};
      i32x4 ridx = {0x7fffffff,0x7fffffff,0x7fffffff,0x7fffffff};

      for (int G=0;G<4;G++){
        f32x4 acc[2][4];
        #pragma unroll
        for (int g=0;g<2;g++)
          #pragma unroll
          for (int m=0;m<4;m++){ f32x4 z = {0.f,0.f,0.f,0.f}; acc[g][m] = z; }

        #pragma unroll
        for (int g=0;g<2;g++){
          int vt = G*2 + g;
          const float* wp = Wfc + (size_t)(blk*VC_ + vt*16 + ln)*512 + 128*wv + 8*lq;
          #pragma unroll
          for (int ks=0;ks<4;ks++){
            f32x4 a0 = *(const f32x4*)(wp + 32*ks);
            f32x4 a1 = *(const f32x4*)(wp + 32*ks + 4);
            s16x8 Bh, Bl; split8(a0, a1, Bh, Bl);
            #pragma unroll
            for (int m=0;m<4;m++){
              acc[g][m] = mfma16(Ah[m][ks], Bh, acc[g][m]);
              acc[g][m] = mfma16(Ah[m][ks], Bl, acc[g][m]);
              acc[g][m] = mfma16(Al[m][ks], Bh, acc[g][m]);
            }
          }
        }
        #pragma unroll
        for (int g=0;g<2;g++)
          #pragma unroll
          for (int m=0;m<4;m++){
            int f4 = (((wv*2+g)*4+m)*4+lq)*16 + ln;
            *(f32x4*)(red + f4*4) = acc[g][m];
          }
        __syncthreads();
        #pragma unroll
        for (int g=0;g<2;g++){
          int vt = G*2+g;
          f32x4 v4 = {0.f,0.f,0.f,0.f};
          #pragma unroll
          for (int ww=0;ww<4;ww++){
            int f4 = (((ww*2+g)*4+wv)*4+lq)*16 + ln;
            v4 += *(const f32x4*)(red + f4*4);
          }
          int vg = blk*VC_ + vt*16 + ln;
          float bias = bfc[vg];
          #pragma unroll
          for (int r=0;r<4;r++){
            float pe = __expf(v4[r] + bias);
            slab[(wv*16 + lq*4 + r)*128 + vt*16 + ln] = pe;
            rsum[r] += pe;
            if (pe > rmax[r]){ rmax[r] = pe; ridx[r] = vg; }  // ascending vg keeps first max
          }
        }
        __syncthreads();
      }

      // combine 16 ln-lanes (same batch quad, disjoint vocab cols)
      #pragma unroll
      for (int d2=1; d2<16; d2<<=1){
        #pragma unroll
        for (int r=0;r<4;r++){
          float os = __shfl_xor(rsum[r], d2, 64);
          float ov = __shfl_xor(rmax[r], d2, 64);
          int   oi = __shfl_xor(ridx[r], d2, 64);
          rsum[r] += os;
          if (ov > rmax[r] || (ov == rmax[r] && oi < ridx[r])){ rmax[r]=ov; ridx[r]=oi; }
        }
      }
      if (ln == 0){
        #pragma unroll
        for (int r=0;r<4;r++){
          int b = wv*16 + lq*4 + r;
          psum [blk*64 + b] = rsum[r];    // [250][64] layout: coalesced reduce
          pmaxv[blk*64 + b] = rmax[r];
          pmaxi[blk*64 + b] = ridx[r];
        }
      }
    }
    gridbar(bar, ++cnt * NBLK);
  }

  // ---- tail: invs(31) via sum-only reduce; row 30 = slab*invs; row 31 = 0 ----
  {
    int b = t & 63, w = t >> 6;
    float sv = 0.f;
    for (int j = w; j < LGRID; j += 4) sv += psum[j*64 + b];
    red[w*64 + b] = sv;
    __syncthreads();
    if (t < 64){
      float S = 0.f;
      #pragma unroll
      for (int ww=0;ww<4;ww++) S += red[ww*64 + t];
      ivs_s[t] = 1.f/S;
    }
    __syncthreads();
  }
  if (blk < LGRID){
    #pragma unroll
    for (int i=0;i<8;i++){
      int e = i*256 + t;
      int b = e >> 5;
      int v4 = (e & 31) << 2;
      f32x4 pv = *(const f32x4*)(slab + b*128 + v4);
      pv *= ivs_s[b];
      __builtin_nontemporal_store(pv,
          (f32x4*)(out + ((size_t)b*T_ + 30)*V_ + blk*VC_ + v4));
      f32x4 z = {0.f,0.f,0.f,0.f};
      __builtin_nontemporal_store(z,
          (f32x4*)(out + ((size_t)b*T_ + 31)*V_ + blk*VC_ + v4));
    }
  }
}

extern "C" void kernel_launch(void* const* d_in, const int* in_sizes, int n_in,
                              void* d_out, int out_size, void* d_ws, size_t ws_size,
                              hipStream_t stream){
  const float* feat = (const float*)d_in[0];
  // d_in[1] = captions: unused by the reference computation
  const float* emb  = (const float*)d_in[2];
  const float* Wih  = (const float*)d_in[3];
  const float* Whh  = (const float*)d_in[4];
  const float* bih  = (const float*)d_in[5];
  const float* bhh  = (const float*)d_in[6];
  const float* Wfc  = (const float*)d_in[7];
  const float* bfc  = (const float*)d_in[8];
  float* out = (float*)d_out;

  char* ws = (char*)d_ws;                                   // ~450 KB used
  unsigned short* xh_hi = (unsigned short*)(ws);            // 64x1024 u16 (h dbuf)
  unsigned short* xh_lo = (unsigned short*)(ws + 131072);   // 64x1024 u16
  float* psum  = (float*)(ws + 262144);                     // [250][64]
  float* pmaxv = (float*)(ws + 327680);                     // [250][64]
  int*   pmaxi = (int*)  (ws + 393216);                     // [250][64]
  int*   bar   = (int*)  (ws + 458752);                     // single counter line

  hipMemsetAsync(bar, 0, 128, stream);

  mega_kernel<<<dim3(NBLK), dim3(256), 0, stream>>>(
      feat, emb, Wih, Whh, bih, bhh, Wfc, bfc, out,
      xh_hi, xh_lo, psum, pmaxv, pmaxi, bar);
}

// Round 6
// 2807.717 us; speedup vs baseline: 2.6649x; 1.6004x over previous
//
#include <hip/hip_runtime.h>

#define E_ 256
#define H_ 512
#define V_ 32000
#define T_ 32
#define LGRID 250   // blocks that own a 128-col vocab chunk
#define VC_ 128
#define NBLK 256    // == CU count: every block resident on its own CU

typedef short s16x8 __attribute__((ext_vector_type(8)));
typedef float f32x4 __attribute__((ext_vector_type(4)));
typedef int   i32x4 __attribute__((ext_vector_type(4)));
typedef unsigned long long u64;

union US8 { i32x4 i; s16x8 s; };

static __device__ __forceinline__ f32x4 mfma16(s16x8 a, s16x8 b, f32x4 c){
  return __builtin_amdgcn_mfma_f32_16x16x32_bf16(a, b, c, 0, 0, 0);
}

static __device__ __forceinline__ unsigned rne(unsigned u){
  return u + 0x7FFFu + ((u >> 16) & 1u);
}

// f32 -> packed dword: bf16(RNE) in hi16, bf16(residual) in lo16
static __device__ __forceinline__ unsigned pack_f(float f){
  unsigned r = rne(__float_as_uint(f));
  float fh = __uint_as_float(r & 0xFFFF0000u);
  unsigned r2 = rne(__float_as_uint(f - fh));
  return (r & 0xFFFF0000u) | (r2 >> 16);
}

// 8 consecutive f32 -> bf16 hi (RNE) + bf16 of residual
static __device__ __forceinline__ void split8(f32x4 a0, f32x4 a1, s16x8 &hi, s16x8 &lo){
  float f[8]; unsigned r[8];
  #pragma unroll
  for (int j=0;j<4;j++){ f[j] = a0[j]; f[4+j] = a1[j]; }
  #pragma unroll
  for (int j=0;j<8;j++) r[j] = rne(__float_as_uint(f[j]));
  US8 Hh, Ll;
  #pragma unroll
  for (int p=0;p<4;p++) Hh.i[p] = (int)__builtin_amdgcn_perm(r[2*p+1], r[2*p], 0x07060302u);
  unsigned d[8];
  #pragma unroll
  for (int j=0;j<8;j++) d[j] = rne(__float_as_uint(f[j] - __uint_as_float(r[j] & 0xFFFF0000u)));
  #pragma unroll
  for (int p=0;p<4;p++) Ll.i[p] = (int)__builtin_amdgcn_perm(d[2*p+1], d[2*p], 0x07060302u);
  hi = Hh.s; lo = Ll.s;
}

// two packed dwordx4 -> hi-plane / lo-plane s16x8 fragments (bit-identical
// to split8's layout: hi16 of packed = bf16 main, lo16 = bf16 residual)
static __device__ __forceinline__ void perm2(i32x4 d0, i32x4 d1, s16x8 &hi, s16x8 &lo){
  US8 H, L;
  H.i[0] = (int)__builtin_amdgcn_perm((unsigned)d0[1], (unsigned)d0[0], 0x07060302u);
  L.i[0] = (int)__builtin_amdgcn_perm((unsigned)d0[1], (unsigned)d0[0], 0x05040100u);
  H.i[1] = (int)__builtin_amdgcn_perm((unsigned)d0[3], (unsigned)d0[2], 0x07060302u);
  L.i[1] = (int)__builtin_amdgcn_perm((unsigned)d0[3], (unsigned)d0[2], 0x05040100u);
  H.i[2] = (int)__builtin_amdgcn_perm((unsigned)d1[1], (unsigned)d1[0], 0x07060302u);
  L.i[2] = (int)__builtin_amdgcn_perm((unsigned)d1[1], (unsigned)d1[0], 0x05040100u);
  H.i[3] = (int)__builtin_amdgcn_perm((unsigned)d1[3], (unsigned)d1[2], 0x07060302u);
  L.i[3] = (int)__builtin_amdgcn_perm((unsigned)d1[3], (unsigned)d1[2], 0x05040100u);
  hi = H.s; lo = L.s;
}

// ============ coherent (sc0 sc1: bypass L1+L2, hit coherence point) ==========
static __device__ __forceinline__ float ld_f32_coh(const float* p){
  float v;
  asm volatile("global_load_dword %0, %1, off sc0 sc1\n\ts_waitcnt vmcnt(0)"
               : "=v"(v) : "v"(p) : "memory");
  return v;
}
static __device__ __forceinline__ u64 ld_u64_coh(const u64* p){
  u64 v;
  asm volatile("global_load_dwordx2 %0, %1, off sc0 sc1\n\ts_waitcnt vmcnt(0)"
               : "=v"(v) : "v"(p) : "memory");
  return v;
}
static __device__ __forceinline__ void st_coh(unsigned* p, unsigned v){
  asm volatile("global_store_dword %0, %1, off sc0 sc1" :: "v"(p), "v"(v) : "memory");
}
static __device__ __forceinline__ void st_coh64(u64* p, u64 v){
  asm volatile("global_store_dwordx2 %0, %1, off sc0 sc1" :: "v"(p), "v"(v) : "memory");
}
// 8 dwordx4 coherent loads (4 frag-pairs, 128B stride), ONE vmcnt wait
static __device__ __forceinline__ void ld_h8o(const unsigned* p,
    i32x4&a0,i32x4&a1,i32x4&b0,i32x4&b1,i32x4&c0,i32x4&c1,i32x4&e0,i32x4&e1){
  asm volatile(
    "global_load_dwordx4 %0, %8, off sc0 sc1\n\t"
    "global_load_dwordx4 %1, %8, off offset:16 sc0 sc1\n\t"
    "global_load_dwordx4 %2, %8, off offset:128 sc0 sc1\n\t"
    "global_load_dwordx4 %3, %8, off offset:144 sc0 sc1\n\t"
    "global_load_dwordx4 %4, %8, off offset:256 sc0 sc1\n\t"
    "global_load_dwordx4 %5, %8, off offset:272 sc0 sc1\n\t"
    "global_load_dwordx4 %6, %8, off offset:384 sc0 sc1\n\t"
    "global_load_dwordx4 %7, %8, off offset:400 sc0 sc1\n\t"
    "s_waitcnt vmcnt(0)"
    : "=&v"(a0),"=&v"(a1),"=&v"(b0),"=&v"(b1),
      "=&v"(c0),"=&v"(c1),"=&v"(e0),"=&v"(e1)
    : "v"(p) : "memory");
}
// 12 dwordx4 coherent loads (6 frag-pairs), ONE vmcnt wait
static __device__ __forceinline__ void ld_h12o(const unsigned* p,
    i32x4&a0,i32x4&a1,i32x4&b0,i32x4&b1,i32x4&c0,i32x4&c1,
    i32x4&e0,i32x4&e1,i32x4&f0,i32x4&f1,i32x4&g0,i32x4&g1){
  asm volatile(
    "global_load_dwordx4 %0, %12, off sc0 sc1\n\t"
    "global_load_dwordx4 %1, %12, off offset:16 sc0 sc1\n\t"
    "global_load_dwordx4 %2, %12, off offset:128 sc0 sc1\n\t"
    "global_load_dwordx4 %3, %12, off offset:144 sc0 sc1\n\t"
    "global_load_dwordx4 %4, %12, off offset:256 sc0 sc1\n\t"
    "global_load_dwordx4 %5, %12, off offset:272 sc0 sc1\n\t"
    "global_load_dwordx4 %6, %12, off offset:384 sc0 sc1\n\t"
    "global_load_dwordx4 %7, %12, off offset:400 sc0 sc1\n\t"
    "global_load_dwordx4 %8, %12, off offset:512 sc0 sc1\n\t"
    "global_load_dwordx4 %9, %12, off offset:528 sc0 sc1\n\t"
    "global_load_dwordx4 %10, %12, off offset:640 sc0 sc1\n\t"
    "global_load_dwordx4 %11, %12, off offset:656 sc0 sc1\n\t"
    "s_waitcnt vmcnt(0)"
    : "=&v"(a0),"=&v"(a1),"=&v"(b0),"=&v"(b1),"=&v"(c0),"=&v"(c1),
      "=&v"(e0),"=&v"(e1),"=&v"(f0),"=&v"(f1),"=&v"(g0),"=&v"(g1)
    : "v"(p) : "memory");
}
// ============ atomics (RMW executes at the coherence point) ==========
static __device__ __forceinline__ void atom_fadd(float* p, float v){
  asm volatile("global_atomic_add_f32 %0, %1, off" :: "v"(p), "v"(v) : "memory");
}
static __device__ __forceinline__ void atom_umax64(u64* p, u64 v){
  asm volatile("global_atomic_umax_x2 %0, %1, off" :: "v"(p), "v"(v) : "memory");
}
static __device__ __forceinline__ void arrive(int* line){
  int one = 1;
  asm volatile("global_atomic_add %0, %1, off" :: "v"(line), "v"(one) : "memory");
}
// poll 8 spread counter lines (128B apart), ONE wait, coherent
static __device__ __forceinline__ int poll8(const int* base){
  int a0,a1,a2,a3,a4,a5,a6,a7;
  asm volatile(
    "global_load_dword %0, %8, off sc0 sc1\n\t"
    "global_load_dword %1, %8, off offset:128 sc0 sc1\n\t"
    "global_load_dword %2, %8, off offset:256 sc0 sc1\n\t"
    "global_load_dword %3, %8, off offset:384 sc0 sc1\n\t"
    "global_load_dword %4, %8, off offset:512 sc0 sc1\n\t"
    "global_load_dword %5, %8, off offset:640 sc0 sc1\n\t"
    "global_load_dword %6, %8, off offset:768 sc0 sc1\n\t"
    "global_load_dword %7, %8, off offset:896 sc0 sc1\n\t"
    "s_waitcnt vmcnt(0)"
    : "=&v"(a0),"=&v"(a1),"=&v"(a2),"=&v"(a3),
      "=&v"(a4),"=&v"(a5),"=&v"(a6),"=&v"(a7)
    : "v"(base) : "memory");
  return a0+a1+a2+a3+a4+a5+a6+a7;
}
static __device__ __forceinline__ void waitsum(const int* lines, int tgt){
  while (poll8(lines) < tgt) __builtin_amdgcn_s_sleep(2);
}

// ---------------------------------------------------------------------------
// Persistent kernel, producer/consumer flags; NO acquire/release cache ops
// anywhere (R3/R4's 60-75us/sync invalidate storms; R5's compiler-relaxed
// atomics hung on stale spins). All cross-block data moves via explicit
// sc0 sc1 instructions; weights use plain cached loads and stay L2-warm.
// Per step s:
//   blocks 0-63 : wait cl>=250s -> read pam/psum_tot totals (2 coherent
//                 scalars/thread; argmax exact via u64-max pack) -> gates(s)
//                 (x from emb[am]/feat plain loads; h via batched coherent
//                 loads) -> publish h -> arrive cg.
//   blocks <250 : wait cg>=64(s+1) -> reset spent accumulator slot ->
//                 out row s-2 = slab(s-1)*ivs(s-1) -> logits(s) -> atomic
//                 accumulate partials -> arrive cl.
// Release = s_waitcnt vmcnt(0) + syncthreads before leader's arrive.
// ---------------------------------------------------------------------------
__global__ __launch_bounds__(256) void mega_kernel(
    const float* __restrict__ feat, const float* __restrict__ emb,
    const float* __restrict__ Wih, const float* __restrict__ Whh,
    const float* __restrict__ bih, const float* __restrict__ bhh,
    const float* __restrict__ Wfc, const float* __restrict__ bfc,
    float* __restrict__ out,
    unsigned* __restrict__ xh,      // [64 b][2 parity][512] packed h dwords
    float* __restrict__ psum_tot,   // [2][64] atomic sum accumulators
    u64*   __restrict__ pam,        // [2][64] atomic packed (maxv, ~vg)
    float* __restrict__ ivs_ws,     // [2][64] published 1/sum
    int* __restrict__ cl, int* __restrict__ cg)
{
  const int blk = blockIdx.x, t = threadIdx.x;
  const int wv = t >> 6, lq = (t >> 4) & 3, ln = t & 15;
  __shared__ float red[8192];     // MFMA cross-wave reduce
  __shared__ float slab[8192];    // [64 b][128 v] exps — persists across steps
  __shared__ float gbuf[2112];    // gates pointwise staging
  __shared__ int   am_s[64];      // gate blocks: argmax per batch
  __shared__ float ivs_l[64];     // vocab blocks: ivs(s-1)

  float creg[2] = {0.f, 0.f};     // LSTM cell state in regs (blk<64)

  #pragma unroll 1
  for (int s = 0; s < T_; ++s){
    const int wr = (s == 0) ? 1 : (s & 1);
    const int rd = wr ^ 1;

    // =================== gate duty: blocks 0-63 ===================
    if (blk < 64){
      if (s >= 1){
        if (t == 0) waitsum(cl, LGRID*s);
        __syncthreads();
        if (t < 64){
          int slot = (s-1)&1;
          u64 P = ld_u64_coh(pam + slot*64 + t);
          am_s[t] = (int)(~(unsigned)P);          // unpack vg (first-max tiebreak)
          if (blk == 0){
            float S = ld_f32_coh(psum_tot + slot*64 + t);
            st_coh((unsigned*)(ivs_ws + slot*64 + t), __float_as_uint(1.f/S));
          }
        }
        __syncthreads();
      }

      // ---- A-fragment gather ----
      s16x8 Agh[4][6], Agl[4][6];
      {
        const s16x8 zz = {0,0,0,0,0,0,0,0};
        if (wv <= 1){                            // x-part (kk<256)
          int nx = (wv==0) ? 6 : 2;
          #pragma unroll
          for (int m=0;m<4;m++){
            int br = m*16 + ln;
            const float* xrow = (s==0) ? (feat + br*E_) : (emb + (size_t)am_s[br]*E_);
            for (int kt=0;kt<nx;kt++){
              int kk = 192*wv + 32*kt + 8*lq;
              f32x4 a0 = *(const f32x4*)(xrow + kk);
              f32x4 a1 = *(const f32x4*)(xrow + kk + 4);
              split8(a0, a1, Agh[m][kt], Agl[m][kt]);
            }
          }
        }
        if (s <= 1){                             // h = 0 (ref discards feature-step state)
          int nx = (wv==0) ? 6 : (wv==1) ? 2 : 0;
          #pragma unroll
          for (int m=0;m<4;m++)
            for (int kt=nx;kt<6;kt++){ Agh[m][kt]=zz; Agl[m][kt]=zz; }
        } else if (wv == 1){                     // h frags kt 2..5
          #pragma unroll
          for (int m=0;m<4;m++){
            int br = m*16 + ln;
            const unsigned* base = xh + br*1024 + rd*512 + 8*lq;
            i32x4 d0,d1,d2,d3,d4,d5,d6,d7;
            ld_h8o(base,d0,d1,d2,d3,d4,d5,d6,d7);
            perm2(d0,d1,Agh[m][2],Agl[m][2]);
            perm2(d2,d3,Agh[m][3],Agl[m][3]);
            perm2(d4,d5,Agh[m][4],Agl[m][4]);
            perm2(d6,d7,Agh[m][5],Agl[m][5]);
          }
        } else if (wv >= 2){                     // h frags kt 0..5
          #pragma unroll
          for (int m=0;m<4;m++){
            int br = m*16 + ln;
            const unsigned* base = xh + br*1024 + rd*512 + (192*wv - 256) + 8*lq;
            i32x4 d0,d1,d2,d3,d4,d5,d6,d7,d8,d9,da,db;
            ld_h12o(base,d0,d1,d2,d3,d4,d5,d6,d7,d8,d9,da,db);
            perm2(d0,d1,Agh[m][0],Agl[m][0]);
            perm2(d2,d3,Agh[m][1],Agl[m][1]);
            perm2(d4,d5,Agh[m][2],Agl[m][2]);
            perm2(d6,d7,Agh[m][3],Agl[m][3]);
            perm2(d8,d9,Agh[m][4],Agl[m][4]);
            perm2(da,db,Agh[m][5],Agl[m][5]);
          }
        }
      }

      f32x4 acc[2][4];
      #pragma unroll
      for (int g=0;g<2;g++)
        #pragma unroll
        for (int m=0;m<4;m++){ f32x4 z = {0.f,0.f,0.f,0.f}; acc[g][m] = z; }

      #pragma unroll
      for (int g=0;g<2;g++){
        int c = blk*32 + g*16 + ln;
        const float* pih = Wih + (size_t)((c&3)*512 + (c>>2))*256;
        const float* phh = Whh + (size_t)((c&3)*512 + (c>>2))*512;
        #pragma unroll
        for (int kt=0;kt<6;kt++){
          int kg = 192*wv + 32*kt;
          int k  = kg + 8*lq;
          const float* p = (kg < 256) ? (pih + k) : (phh + (k - 256));
          f32x4 a0 = *(const f32x4*)p;
          f32x4 a1 = *(const f32x4*)(p + 4);
          s16x8 Bh, Bl; split8(a0, a1, Bh, Bl);
          #pragma unroll
          for (int m=0;m<4;m++){
            acc[g][m] = mfma16(Agh[m][kt], Bh, acc[g][m]);
            acc[g][m] = mfma16(Agh[m][kt], Bl, acc[g][m]);
            acc[g][m] = mfma16(Agl[m][kt], Bh, acc[g][m]);
          }
        }
      }
      #pragma unroll
      for (int g=0;g<2;g++)
        #pragma unroll
        for (int m=0;m<4;m++){
          int f4 = (((wv*2+g)*4+m)*4+lq)*16 + ln;
          *(f32x4*)(red + f4*4) = acc[g][m];
        }
      __syncthreads();
      #pragma unroll
      for (int g=0;g<2;g++){
        f32x4 v4 = {0.f,0.f,0.f,0.f};
        #pragma unroll
        for (int ww=0;ww<4;ww++){
          int f4 = (((ww*2+g)*4+wv)*4+lq)*16 + ln;
          v4 += *(const f32x4*)(red + f4*4);
        }
        int c = blk*32 + g*16 + ln;
        int row = (c&3)*512 + (c>>2);
        float bias = bih[row] + bhh[row];
        #pragma unroll
        for (int r=0;r<4;r++)
          gbuf[(wv*16 + lq*4 + r)*33 + g*16 + ln] = v4[r] + bias;
      }
      __syncthreads();
      #pragma unroll
      for (int rep=0;rep<2;rep++){
        int p = rep*256 + t;
        int b = p >> 3, ul = p & 7;
        float gi = gbuf[b*33 + ul*4 + 0];
        float gf = gbuf[b*33 + ul*4 + 1];
        float gg = gbuf[b*33 + ul*4 + 2];
        float go = gbuf[b*33 + ul*4 + 3];
        int u = blk*8 + ul;
        float cp = (s <= 1) ? 0.f : creg[rep];   // ref restarts state after feature step
        float si = 1.f/(1.f + __expf(-gi));
        float sf = 1.f/(1.f + __expf(-gf));
        float so = 1.f/(1.f + __expf(-go));
        float cn = sf*cp + si*tanhf(gg);
        creg[rep] = cn;
        float hv = so*tanhf(cn);
        st_coh(xh + b*1024 + wr*512 + u, pack_f(hv));
      }
      // publish h(s): drain all waves' coherent stores, then arrive
      asm volatile("s_waitcnt vmcnt(0)" ::: "memory");
      __syncthreads();
      if (t == 0) arrive(cg + (blk & 7)*32);
    }

    // =================== vocab duty: blocks 0-249 ===================
    if (blk < LGRID){
      if (t == 0) waitsum(cg, 64*(s+1));
      __syncthreads();

      // reset the accumulator slot gates just consumed (idempotent zeros;
      // all gate reads finished before cg completed); read ivs(s-1)
      if (t < 64){
        int slot = (s-1)&1;
        st_coh((unsigned*)(psum_tot + slot*64 + t), 0u);
        st_coh64(pam + slot*64 + t, 0ull);
        if (s >= 2) ivs_l[t] = ld_f32_coh(ivs_ws + slot*64 + t);
      }

      if (s >= 2){
        __syncthreads();
        #pragma unroll
        for (int i=0;i<8;i++){
          int e = i*256 + t;
          int b = e >> 5;
          int v4 = (e & 31) << 2;
          f32x4 pv = *(const f32x4*)(slab + b*128 + v4);
          pv *= ivs_l[b];
          __builtin_nontemporal_store(pv,
              (f32x4*)(out + ((size_t)b*T_ + (s-2))*V_ + blk*VC_ + v4));
        }
      }

      // ---- logits: h frags via batched coherent loads ----
      s16x8 Ah[4][4], Al[4][4];
      #pragma unroll
      for (int m=0;m<4;m++){
        int br = m*16 + ln;
        const unsigned* base = xh + br*1024 + wr*512 + 128*wv + 8*lq;
        i32x4 d0,d1,d2,d3,d4,d5,d6,d7;
        ld_h8o(base,d0,d1,d2,d3,d4,d5,d6,d7);
        perm2(d0,d1,Ah[m][0],Al[m][0]);
        perm2(d2,d3,Ah[m][1],Al[m][1]);
        perm2(d4,d5,Ah[m][2],Al[m][2]);
        perm2(d6,d7,Ah[m][3],Al[m][3]);
      }

      f32x4 rsum = {0.f,0.f,0.f,0.f};
      f32x4 rmax = {-1e30f,-1e30f,-1e30f,-1e30f};
      i32x4 ridx = {0x7fffffff,0x7fffffff,0x7fffffff,0x7fffffff};

      for (int G=0;G<4;G++){
        f32x4 acc[2][4];
        #pragma unroll
        for (int g=0;g<2;g++)
          #pragma unroll
          for (int m=0;m<4;m++){ f32x4 z = {0.f,0.f,0.f,0.f}; acc[g][m] = z; }

        #pragma unroll
        for (int g=0;g<2;g++){
          int vt = G*2 + g;
          const float* wp = Wfc + (size_t)(blk*VC_ + vt*16 + ln)*512 + 128*wv + 8*lq;
          #pragma unroll
          for (int ks=0;ks<4;ks++){
            f32x4 a0 = *(const f32x4*)(wp + 32*ks);
            f32x4 a1 = *(const f32x4*)(wp + 32*ks + 4);
            s16x8 Bh, Bl; split8(a0, a1, Bh, Bl);
            #pragma unroll
            for (int m=0;m<4;m++){
              acc[g][m] = mfma16(Ah[m][ks], Bh, acc[g][m]);
              acc[g][m] = mfma16(Ah[m][ks], Bl, acc[g][m]);
              acc[g][m] = mfma16(Al[m][ks], Bh, acc[g][m]);
            }
          }
        }
        #pragma unroll
        for (int g=0;g<2;g++)
          #pragma unroll
          for (int m=0;m<4;m++){
            int f4 = (((wv*2+g)*4+m)*4+lq)*16 + ln;
            *(f32x4*)(red + f4*4) = acc[g][m];
          }
        __syncthreads();
        #pragma unroll
        for (int g=0;g<2;g++){
          int vt = G*2+g;
          f32x4 v4 = {0.f,0.f,0.f,0.f};
          #pragma unroll
          for (int ww=0;ww<4;ww++){
            int f4 = (((ww*2+g)*4+wv)*4+lq)*16 + ln;
            v4 += *(const f32x4*)(red + f4*4);
          }
          int vg = blk*VC_ + vt*16 + ln;
          float bias = bfc[vg];
          #pragma unroll
          for (int r=0;r<4;r++){
            float pe = __expf(v4[r] + bias);
            slab[(wv*16 + lq*4 + r)*128 + vt*16 + ln] = pe;
            rsum[r] += pe;
            if (pe > rmax[r]){ rmax[r] = pe; ridx[r] = vg; }  // ascending vg keeps first max
          }
        }
        __syncthreads();
      }

      // combine 16 ln-lanes (same batch quad, disjoint vocab cols)
      #pragma unroll
      for (int d2=1; d2<16; d2<<=1){
        #pragma unroll
        for (int r=0;r<4;r++){
          float os = __shfl_xor(rsum[r], d2, 64);
          float ov = __shfl_xor(rmax[r], d2, 64);
          int   oi = __shfl_xor(ridx[r], d2, 64);
          rsum[r] += os;
          if (ov > rmax[r] || (ov == rmax[r] && oi < ridx[r])){ rmax[r]=ov; ridx[r]=oi; }
        }
      }
      if (ln == 0){
        int aslot = s & 1;
        #pragma unroll
        for (int r=0;r<4;r++){
          int b = wv*16 + lq*4 + r;
          atom_fadd(psum_tot + aslot*64 + b, rsum[r]);
          u64 pk = ((u64)__float_as_uint(rmax[r]) << 32) | (unsigned)(~ridx[r]);
          atom_umax64(pam + aslot*64 + b, pk);   // exp>0 -> f32 bits order-preserving
        }
      }
      // publish partials(s)
      asm volatile("s_waitcnt vmcnt(0)" ::: "memory");
      __syncthreads();
      if (t == 0) arrive(cl + (blk & 7)*32);
    }
  }

  // ---- tail: ivs(31) from slot 1 totals; row 30 = slab*ivs; row 31 = 0 ----
  if (blk < LGRID){
    if (t == 0) waitsum(cl, LGRID*T_);
    __syncthreads();
    if (t < 64) ivs_l[t] = 1.f / ld_f32_coh(psum_tot + 64 + t);  // slot (T_-1)&1 = 1
    __syncthreads();
    #pragma unroll
    for (int i=0;i<8;i++){
      int e = i*256 + t;
      int bb = e >> 5;
      int v4 = (e & 31) << 2;
      f32x4 pv = *(const f32x4*)(slab + bb*128 + v4);
      pv *= ivs_l[bb];
      __builtin_nontemporal_store(pv,
          (f32x4*)(out + ((size_t)bb*T_ + 30)*V_ + blk*VC_ + v4));
      f32x4 z = {0.f,0.f,0.f,0.f};
      __builtin_nontemporal_store(z,
          (f32x4*)(out + ((size_t)bb*T_ + 31)*V_ + blk*VC_ + v4));
    }
  }
}

extern "C" void kernel_launch(void* const* d_in, const int* in_sizes, int n_in,
                              void* d_out, int out_size, void* d_ws, size_t ws_size,
                              hipStream_t stream){
  const float* feat = (const float*)d_in[0];
  // d_in[1] = captions: unused by the reference computation
  const float* emb  = (const float*)d_in[2];
  const float* Wih  = (const float*)d_in[3];
  const float* Whh  = (const float*)d_in[4];
  const float* bih  = (const float*)d_in[5];
  const float* bhh  = (const float*)d_in[6];
  const float* Wfc  = (const float*)d_in[7];
  const float* bfc  = (const float*)d_in[8];
  float* out = (float*)d_out;

  char* ws = (char*)d_ws;                                   // ~260 KB used
  unsigned* xh     = (unsigned*)(ws);                       // [64][2][512] dwords
  float*    psum_t = (float*)  (ws + 262144);               // [2][64]
  u64*      pam    = (u64*)    (ws + 262656);               // [2][64]
  float*    ivs_ws = (float*)  (ws + 263680);               // [2][64]
  int*      cl     = (int*)    (ws + 264192);               // 8 x 128B lines
  int*      cg     = (int*)    (ws + 265216);               // 8 x 128B lines

  hipMemsetAsync(ws + 262144, 0, 4096, stream);             // accs + flags

  mega_kernel<<<dim3(NBLK), dim3(256), 0, stream>>>(
      feat, emb, Wih, Whh, bih, bhh, Wfc, bfc, out,
      xh, psum_t, pam, ivs_ws, cl, cg);
}